// Round 5
// baseline (2406.625 us; speedup 1.0000x reference)
//
#include <hip/hip_runtime.h>

#define S_LEN 2048
#define NHQ 32
#define NKV 8
#define HD 64
#define DMODEL 2048   // NHQ*HD
#define DKV 512       // NKV*HD

typedef unsigned short ushort_t;
typedef unsigned int uint_t;

__device__ __forceinline__ float b2f(ushort_t h) {
  union { uint_t u; float f; } v;
  v.u = ((uint_t)h) << 16;
  return v.f;
}
// round-to-nearest-even fp32 -> bf16
__device__ __forceinline__ ushort_t f2b(float f) {
  union { float f; uint_t u; } v;
  v.f = f;
  uint_t r = v.u + 0x7fffu + ((v.u >> 16) & 1u);
  return (ushort_t)(r >> 16);
}

union U4 { uint4 v; ushort_t s[8]; };

__device__ __forceinline__ float ldf(const float* p) { return *p; }
__device__ __forceinline__ float ldf(const ushort_t* p) { return b2f(*p); }
__device__ __forceinline__ void stf(float* p, float v) { *p = v; }
__device__ __forceinline__ void stf(ushort_t* p, float v) { *p = f2b(v); }

// load 8 consecutive elements as fp32
__device__ __forceinline__ void load8(const float* p, float* d) {
  float4 a = *(const float4*)p;
  float4 b = *(const float4*)(p + 4);
  d[0] = a.x; d[1] = a.y; d[2] = a.z; d[3] = a.w;
  d[4] = b.x; d[5] = b.y; d[6] = b.z; d[7] = b.w;
}
__device__ __forceinline__ void load8(const ushort_t* p, float* d) {
  U4 a; a.v = *(const uint4*)p;
  #pragma unroll
  for (int j = 0; j < 8; ++j) d[j] = b2f(a.s[j]);
}
// store 8 consecutive fp32 values as TC
__device__ __forceinline__ void store8(float* p, const float* v) {
  *(float4*)p       = make_float4(v[0], v[1], v[2], v[3]);
  *(float4*)(p + 4) = make_float4(v[4], v[5], v[6], v[7]);
}
__device__ __forceinline__ void store8(ushort_t* p, const float* v) {
  U4 c;
  #pragma unroll
  for (int j = 0; j < 8; ++j) c.s[j] = f2b(v[j]);
  *(uint4*)p = c.v;
}

// C[M,N] = A[M,K] @ B[K,N]; row-major; fp32 accumulate. M%128==0, N%128==0, K%16==0.
template<typename TA, typename TB, typename TC>
__global__ __launch_bounds__(256) void gemm_any(const TA* __restrict__ A,
                                                const TB* __restrict__ B,
                                                TC* __restrict__ C,
                                                int M, int N, int K) {
  __shared__ float As[16][128];   // As[k][m]
  __shared__ float Bs[16][132];   // Bs[k][n], +4 pad
  const int tid = threadIdx.x;
  const int bx = blockIdx.x, by = blockIdx.y;
  const int tx = tid & 15, ty = tid >> 4;
  const int am = tid >> 1, ak = (tid & 1) * 8;   // A staging: row am, k-offset ak
  const int bk = tid >> 4, bn = (tid & 15) * 8;  // B staging: k-row bk, col bn

  float acc[8][8];
  #pragma unroll
  for (int i = 0; i < 8; ++i)
    #pragma unroll
    for (int j = 0; j < 8; ++j) acc[i][j] = 0.f;

  const TA* aptr = A + (size_t)(by * 128 + am) * K + ak;
  const TB* bptr = B + (size_t)bk * N + bx * 128 + bn;

  for (int kt = 0; kt < K; kt += 16) {
    float av8[8], bv8[8];
    load8(aptr + kt, av8);
    load8(bptr + (size_t)kt * N, bv8);
    #pragma unroll
    for (int j = 0; j < 8; ++j) As[ak + j][am] = av8[j];
    #pragma unroll
    for (int j = 0; j < 8; ++j) Bs[bk][bn + j] = bv8[j];
    __syncthreads();
    #pragma unroll
    for (int kk = 0; kk < 16; ++kk) {
      float av[8], bv[8];
      #pragma unroll
      for (int i = 0; i < 8; ++i) av[i] = As[kk][ty * 8 + i];
      #pragma unroll
      for (int j = 0; j < 8; ++j) bv[j] = Bs[kk][tx * 8 + j];
      #pragma unroll
      for (int i = 0; i < 8; ++i)
        #pragma unroll
        for (int j = 0; j < 8; ++j) acc[i][j] += av[i] * bv[j];
    }
    __syncthreads();
  }
  #pragma unroll
  for (int i = 0; i < 8; ++i)
    store8(C + (size_t)(by * 128 + ty * 8 + i) * N + bx * 128 + tx * 8, acc[i]);
}

// RoPE in-place on buffer [S, nh, 64] (bf16 or fp32); cos/sin fp32 [S, 64]
// (duplicated halves, use [:32]). One thread per (row, head, d<32); each
// thread exclusively owns its (d, d+32) pair -> in-place safe.
template<typename T>
__global__ void rope_kernel(T* buf,
                            const float* __restrict__ cosT, const float* __restrict__ sinT,
                            int nh) {
  int idx = blockIdx.x * blockDim.x + threadIdx.x;
  int total = S_LEN * nh * 32;
  if (idx >= total) return;
  int d = idx & 31;
  int h = (idx >> 5) & (nh - 1);
  int r = idx / (nh * 32);
  size_t base = (size_t)r * nh * 64 + h * 64 + d;
  float x1 = ldf(buf + base);
  float x2 = ldf(buf + base + 32);
  float c = cosT[r * 64 + d];
  float s = sinT[r * 64 + d];
  stf(buf + base, x1 * c - x2 * s);
  stf(buf + base + 32, x1 * s + x2 * c);
}

// Flash-style causal GQA attention. Q/O bf16 (in ws, in-place safe: block
// (r0,h) reads exactly the q patch it alone overwrites at the end);
// K/V fp32 (in d_out regions). Block = 4 waves = 4 query rows of one head.
// K/V staged in 64-key LDS fp32 tiles (stride 65 -> <=2-way conflicts, free).
__global__ __launch_bounds__(256) void attn_kernel(const ushort_t* Q,
                                                   const float* __restrict__ Kc,
                                                   const float* __restrict__ Vc,
                                                   ushort_t* O) {
  __shared__ float Ks[64][65];
  __shared__ float Vs[64][65];
  __shared__ float qs[4][64];
  __shared__ float ps[4][64];
  const int h = blockIdx.y;
  const int r0 = blockIdx.x * 4;
  const int hk = h >> 2;           // N_REP = 4
  const int tid = threadIdx.x;
  const int w = tid >> 6;
  const int lane = tid & 63;
  const int row = r0 + w;

  qs[w][lane] = b2f(Q[(size_t)row * DMODEL + h * HD + lane]);

  float m = -1e30f, lsum = 0.f, oacc = 0.f;  // lane owns output dim `lane` of its row
  const int ntiles = (r0 + 3) / 64 + 1;      // uniform across the block
  const int key = tid >> 2;                  // staging: thread loads 16 elems of one key
  const int part = (tid & 3) * 16;
  for (int t = 0; t < ntiles; ++t) {
    const int base = t * 64;
    __syncthreads();  // previous tile fully consumed before overwrite (covers qs at t=0)
    const float* kp = Kc + (size_t)(base + key) * DKV + hk * HD + part;
    const float* vp = Vc + (size_t)(base + key) * DKV + hk * HD + part;
    float kv[16], vv[16];
    *(float4*)(kv)      = *(const float4*)kp;
    *(float4*)(kv + 4)  = *(const float4*)(kp + 4);
    *(float4*)(kv + 8)  = *(const float4*)(kp + 8);
    *(float4*)(kv + 12) = *(const float4*)(kp + 12);
    *(float4*)(vv)      = *(const float4*)vp;
    *(float4*)(vv + 4)  = *(const float4*)(vp + 4);
    *(float4*)(vv + 8)  = *(const float4*)(vp + 8);
    *(float4*)(vv + 12) = *(const float4*)(vp + 12);
    #pragma unroll
    for (int j = 0; j < 16; ++j) {
      Ks[key][part + j] = kv[j];
      Vs[key][part + j] = vv[j];
    }
    __syncthreads();
    // score for key base+lane
    float s = 0.f;
    #pragma unroll
    for (int d = 0; d < 64; ++d) s += qs[w][d] * Ks[lane][d];
    s *= 0.125f;                               // 1/sqrt(64)
    if (base + lane > row) s -= 1e9f;          // additive causal mask, like reference
    float tmax = s;
    #pragma unroll
    for (int off = 32; off > 0; off >>= 1) tmax = fmaxf(tmax, __shfl_xor(tmax, off));
    const float mnew = fmaxf(m, tmax);
    const float alpha = __expf(m - mnew);
    float p = __expf(s - mnew);
    float psum = p;
    #pragma unroll
    for (int off = 32; off > 0; off >>= 1) psum += __shfl_xor(psum, off);
    lsum = lsum * alpha + psum;
    m = mnew;
    ps[w][lane] = p;
    __syncthreads();
    float acc = 0.f;
    #pragma unroll
    for (int l = 0; l < 64; ++l) acc += ps[w][l] * Vs[l][lane];
    oacc = oacc * alpha + acc;
  }
  O[(size_t)row * DMODEL + h * HD + lane] = f2b(oacc / lsum);
}

extern "C" void kernel_launch(void* const* d_in, const int* in_sizes, int n_in,
                              void* d_out, int out_size, void* d_ws, size_t ws_size,
                              hipStream_t stream) {
  // Inputs fp32; OUTPUT BUFFER IS FP32 (reference output dtype = float32).
  const float* x    = (const float*)d_in[0];
  const float* cosT = (const float*)d_in[1];
  const float* sinT = (const float*)d_in[2];
  // d_in[3] = mask: causal -1e9, applied analytically (identical semantics)
  const float* wq   = (const float*)d_in[4];
  const float* wk   = (const float*)d_in[5];
  const float* wv   = (const float*)d_in[6];
  const float* wo   = (const float*)d_in[7];

  float* out   = (float*)d_out;                    // [S, 2048] fp32
  float* out_k = out + (size_t)S_LEN * DMODEL;     // new_k [S, 8, 64] fp32
  float* out_v = out_k + (size_t)S_LEN * DKV;      // new_v [S, 8, 64] fp32

  ushort_t* ws_q = (ushort_t*)d_ws;                // q [S, 2048] bf16 = 8 MB

  dim3 blk(256);
  // projections: q (bf16) to ws; k, v (fp32) straight to output regions
  gemm_any<float, float, ushort_t><<<dim3(DMODEL / 128, S_LEN / 128), blk, 0, stream>>>(x, wq, ws_q, S_LEN, DMODEL, DMODEL);
  gemm_any<float, float, float>   <<<dim3(DKV / 128,    S_LEN / 128), blk, 0, stream>>>(x, wk, out_k, S_LEN, DKV, DMODEL);
  gemm_any<float, float, float>   <<<dim3(DKV / 128,    S_LEN / 128), blk, 0, stream>>>(x, wv, out_v, S_LEN, DKV, DMODEL);
  // rope in-place: q (bf16) in ws, k (fp32) in new_k output region
  rope_kernel<ushort_t><<<(S_LEN * NHQ * 32 + 255) / 256, 256, 0, stream>>>(ws_q, cosT, sinT, NHQ);
  rope_kernel<float>   <<<(S_LEN * NKV * 32 + 255) / 256, 256, 0, stream>>>(out_k, cosT, sinT, NKV);
  // attention, in-place on q
  attn_kernel<<<dim3(S_LEN / 4, NHQ), 256, 0, stream>>>(ws_q, out_k, out_v, ws_q);
  // output projection: bf16 attn_out x fp32 wo -> fp32 out
  gemm_any<ushort_t, float, float><<<dim3(DMODEL / 128, S_LEN / 128), blk, 0, stream>>>(ws_q, wo, out, S_LEN, DMODEL, DMODEL);
}

// Round 6
// 1699.003 us; speedup vs baseline: 1.4165x; 1.4165x over previous
//
#include <hip/hip_runtime.h>

#define S_LEN 2048
#define NHQ 32
#define NKV 8
#define HD 64
#define DMODEL 2048   // NHQ*HD
#define DKV 512       // NKV*HD

typedef unsigned short ushort_t;
typedef unsigned int uint_t;

typedef __attribute__((ext_vector_type(8))) short bf16x8;
typedef __attribute__((ext_vector_type(4))) float f32x4;

__device__ __forceinline__ float b2f(ushort_t h) {
  union { uint_t u; float f; } v;
  v.u = ((uint_t)h) << 16;
  return v.f;
}
// round-to-nearest-even fp32 -> bf16
__device__ __forceinline__ ushort_t f2b(float f) {
  union { float f; uint_t u; } v;
  v.f = f;
  uint_t r = v.u + 0x7fffu + ((v.u >> 16) & 1u);
  return (ushort_t)(r >> 16);
}
__device__ __forceinline__ uint_t pack2(float lo, float hi) {
  return (uint_t)f2b(lo) | ((uint_t)f2b(hi) << 16);
}

__device__ __forceinline__ void stf(float* p, float v) { *p = v; }
__device__ __forceinline__ void stf(ushort_t* p, float v) { *p = f2b(v); }

union BF8 { uint4 v; ushort_t s[8]; };

// load 16 consecutive elements, convert to 16 bf16 packed in two uint4
__device__ __forceinline__ void load16cvt(const float* p, uint4& lo, uint4& hi) {
  const float4* q = (const float4*)p;
  float4 f0 = q[0], f1 = q[1], f2 = q[2], f3 = q[3];
  BF8 u0, u1;
  u0.s[0] = f2b(f0.x); u0.s[1] = f2b(f0.y); u0.s[2] = f2b(f0.z); u0.s[3] = f2b(f0.w);
  u0.s[4] = f2b(f1.x); u0.s[5] = f2b(f1.y); u0.s[6] = f2b(f1.z); u0.s[7] = f2b(f1.w);
  u1.s[0] = f2b(f2.x); u1.s[1] = f2b(f2.y); u1.s[2] = f2b(f2.z); u1.s[3] = f2b(f2.w);
  u1.s[4] = f2b(f3.x); u1.s[5] = f2b(f3.y); u1.s[6] = f2b(f3.z); u1.s[7] = f2b(f3.w);
  lo = u0.v; hi = u1.v;
}
__device__ __forceinline__ void load16cvt(const ushort_t* p, uint4& lo, uint4& hi) {
  lo = ((const uint4*)p)[0]; hi = ((const uint4*)p)[1];
}

// MFMA GEMM: C[M,N] = A[M,K] @ B[K,N]; A fp32-or-bf16 row-major, B fp32
// row-major, C fp32-or-bf16, fp32 accumulate via v_mfma_f32_16x16x32_bf16.
// Block 256 thr = 4 waves; tile 128x128, BK=32; each wave owns a 64x64
// quadrant (4x4 grid of 16x16 MFMA tiles). B is staged TRANSPOSED into LDS
// (BsT[n][k], stride 40 -> rows 16B-aligned) so both fragments are
// single ds_read_b128. Requires M%128==0, N%128==0, K%32==0.
template<typename TA, typename TC>
__global__ __launch_bounds__(256) void gemm_mfma(const TA* __restrict__ A,
                                                 const float* __restrict__ B,
                                                 TC* __restrict__ C,
                                                 int M, int N, int K) {
  __shared__ ushort_t As[128][32];    // [m][k]  8 KB
  __shared__ ushort_t BsT[128][40];   // [n][k] 10 KB (cols 0..31 used)
  const int tid = threadIdx.x;
  const int lane = tid & 63;
  const int w = tid >> 6;
  const int wr = (w >> 1) * 64, wc = (w & 1) * 64;   // wave quadrant
  const int lm = lane & 15, kq = lane >> 4;          // MFMA lane coords
  const int tile_m = blockIdx.y * 128, tile_n = blockIdx.x * 128;

  const int am = tid >> 1, ak = (tid & 1) * 16;      // A staging map
  const int kp = tid >> 4, np2 = (tid & 15) * 2;     // B staging map

  f32x4 acc[4][4];
  #pragma unroll
  for (int i = 0; i < 4; ++i)
    #pragma unroll
    for (int j = 0; j < 4; ++j) acc[i][j] = {0.f, 0.f, 0.f, 0.f};

  for (int kt = 0; kt < K; kt += 32) {
    __syncthreads();   // previous tile fully consumed before overwrite
    // ---- stage A tile (128x32), fp32->bf16 in registers ----
    uint4 lo, hi;
    load16cvt(A + (size_t)(tile_m + am) * K + kt + ak, lo, hi);
    *(uint4*)&As[am][ak]     = lo;
    *(uint4*)&As[am][ak + 8] = hi;
    // ---- stage B tile (32x128) transposed: BsT[n][k] ----
    const float* bp = B + (size_t)(kt + 2 * kp) * N + tile_n;
    #pragma unroll
    for (int j = 0; j < 4; ++j) {
      const int n = np2 + 32 * j;
      float2 r0 = *(const float2*)(bp + n);
      float2 r1 = *(const float2*)(bp + N + n);
      *(uint_t*)&BsT[n][2 * kp]     = pack2(r0.x, r1.x);
      *(uint_t*)&BsT[n + 1][2 * kp] = pack2(r0.y, r1.y);
    }
    __syncthreads();
    // ---- fragments + 16 MFMA ----
    bf16x8 af[4], bfr[4];
    #pragma unroll
    for (int i = 0; i < 4; ++i) af[i]  = *(const bf16x8*)&As[wr + 16 * i + lm][kq * 8];
    #pragma unroll
    for (int j = 0; j < 4; ++j) bfr[j] = *(const bf16x8*)&BsT[wc + 16 * j + lm][kq * 8];
    #pragma unroll
    for (int i = 0; i < 4; ++i)
      #pragma unroll
      for (int j = 0; j < 4; ++j)
        acc[i][j] = __builtin_amdgcn_mfma_f32_16x16x32_bf16(af[i], bfr[j], acc[i][j], 0, 0, 0);
  }
  // ---- epilogue: C/D layout col=lane&15, row=(lane>>4)*4+reg ----
  #pragma unroll
  for (int i = 0; i < 4; ++i)
    #pragma unroll
    for (int j = 0; j < 4; ++j)
      #pragma unroll
      for (int r = 0; r < 4; ++r) {
        const int row = tile_m + wr + 16 * i + kq * 4 + r;
        const int col = tile_n + wc + 16 * j + lm;
        stf(C + (size_t)row * N + col, acc[i][j][r]);
      }
}

// RoPE in-place on buffer [S, nh, 64] (bf16 or fp32); cos/sin fp32 [S, 64]
// (duplicated halves, use [:32]). One thread per (row, head, d<32); each
// thread exclusively owns its (d, d+32) pair -> in-place safe.
__device__ __forceinline__ float ldf(const float* p) { return *p; }
__device__ __forceinline__ float ldf(const ushort_t* p) { return b2f(*p); }

template<typename T>
__global__ void rope_kernel(T* buf,
                            const float* __restrict__ cosT, const float* __restrict__ sinT,
                            int nh) {
  int idx = blockIdx.x * blockDim.x + threadIdx.x;
  int total = S_LEN * nh * 32;
  if (idx >= total) return;
  int d = idx & 31;
  int h = (idx >> 5) & (nh - 1);
  int r = idx / (nh * 32);
  size_t base = (size_t)r * nh * 64 + h * 64 + d;
  float x1 = ldf(buf + base);
  float x2 = ldf(buf + base + 32);
  float c = cosT[r * 64 + d];
  float s = sinT[r * 64 + d];
  stf(buf + base, x1 * c - x2 * s);
  stf(buf + base + 32, x1 * s + x2 * c);
}

// Flash-style causal GQA attention (unchanged from verified round 5).
__global__ __launch_bounds__(256) void attn_kernel(const ushort_t* Q,
                                                   const float* __restrict__ Kc,
                                                   const float* __restrict__ Vc,
                                                   ushort_t* O) {
  __shared__ float Ks[64][65];
  __shared__ float Vs[64][65];
  __shared__ float qs[4][64];
  __shared__ float ps[4][64];
  const int h = blockIdx.y;
  const int r0 = blockIdx.x * 4;
  const int hk = h >> 2;           // N_REP = 4
  const int tid = threadIdx.x;
  const int w = tid >> 6;
  const int lane = tid & 63;
  const int row = r0 + w;

  qs[w][lane] = b2f(Q[(size_t)row * DMODEL + h * HD + lane]);

  float m = -1e30f, lsum = 0.f, oacc = 0.f;
  const int ntiles = (r0 + 3) / 64 + 1;
  const int key = tid >> 2;
  const int part = (tid & 3) * 16;
  for (int t = 0; t < ntiles; ++t) {
    const int base = t * 64;
    __syncthreads();
    const float* kp = Kc + (size_t)(base + key) * DKV + hk * HD + part;
    const float* vp = Vc + (size_t)(base + key) * DKV + hk * HD + part;
    float kv[16], vv[16];
    *(float4*)(kv)      = *(const float4*)kp;
    *(float4*)(kv + 4)  = *(const float4*)(kp + 4);
    *(float4*)(kv + 8)  = *(const float4*)(kp + 8);
    *(float4*)(kv + 12) = *(const float4*)(kp + 12);
    *(float4*)(vv)      = *(const float4*)vp;
    *(float4*)(vv + 4)  = *(const float4*)(vp + 4);
    *(float4*)(vv + 8)  = *(const float4*)(vp + 8);
    *(float4*)(vv + 12) = *(const float4*)(vp + 12);
    #pragma unroll
    for (int j = 0; j < 16; ++j) {
      Ks[key][part + j] = kv[j];
      Vs[key][part + j] = vv[j];
    }
    __syncthreads();
    float s = 0.f;
    #pragma unroll
    for (int d = 0; d < 64; ++d) s += qs[w][d] * Ks[lane][d];
    s *= 0.125f;
    if (base + lane > row) s -= 1e9f;
    float tmax = s;
    #pragma unroll
    for (int off = 32; off > 0; off >>= 1) tmax = fmaxf(tmax, __shfl_xor(tmax, off));
    const float mnew = fmaxf(m, tmax);
    const float alpha = __expf(m - mnew);
    float p = __expf(s - mnew);
    float psum = p;
    #pragma unroll
    for (int off = 32; off > 0; off >>= 1) psum += __shfl_xor(psum, off);
    lsum = lsum * alpha + psum;
    m = mnew;
    ps[w][lane] = p;
    __syncthreads();
    float acc = 0.f;
    #pragma unroll
    for (int l = 0; l < 64; ++l) acc += ps[w][l] * Vs[l][lane];
    oacc = oacc * alpha + acc;
  }
  O[(size_t)row * DMODEL + h * HD + lane] = f2b(oacc / lsum);
}

extern "C" void kernel_launch(void* const* d_in, const int* in_sizes, int n_in,
                              void* d_out, int out_size, void* d_ws, size_t ws_size,
                              hipStream_t stream) {
  const float* x    = (const float*)d_in[0];
  const float* cosT = (const float*)d_in[1];
  const float* sinT = (const float*)d_in[2];
  // d_in[3] = mask: causal -1e9, applied analytically (identical semantics)
  const float* wq   = (const float*)d_in[4];
  const float* wk   = (const float*)d_in[5];
  const float* wv   = (const float*)d_in[6];
  const float* wo   = (const float*)d_in[7];

  float* out   = (float*)d_out;                    // [S, 2048] fp32
  float* out_k = out + (size_t)S_LEN * DMODEL;     // new_k [S, 8, 64] fp32
  float* out_v = out_k + (size_t)S_LEN * DKV;      // new_v [S, 8, 64] fp32

  ushort_t* ws_q = (ushort_t*)d_ws;                // q [S, 2048] bf16 = 8 MB

  dim3 blk(256);
  // projections via MFMA: q (bf16) to ws; k, v (fp32) straight to output regions
  gemm_mfma<float, ushort_t><<<dim3(DMODEL / 128, S_LEN / 128), blk, 0, stream>>>(x, wq, ws_q, S_LEN, DMODEL, DMODEL);
  gemm_mfma<float, float>   <<<dim3(DKV / 128,    S_LEN / 128), blk, 0, stream>>>(x, wk, out_k, S_LEN, DKV, DMODEL);
  gemm_mfma<float, float>   <<<dim3(DKV / 128,    S_LEN / 128), blk, 0, stream>>>(x, wv, out_v, S_LEN, DKV, DMODEL);
  // rope in-place: q (bf16) in ws, k (fp32) in new_k output region
  rope_kernel<ushort_t><<<(S_LEN * NHQ * 32 + 255) / 256, 256, 0, stream>>>(ws_q, cosT, sinT, NHQ);
  rope_kernel<float>   <<<(S_LEN * NKV * 32 + 255) / 256, 256, 0, stream>>>(out_k, cosT, sinT, NKV);
  // attention, in-place on q
  attn_kernel<<<dim3(S_LEN / 4, NHQ), 256, 0, stream>>>(ws_q, out_k, out_v, ws_q);
  // output projection: bf16 attn_out x fp32 wo -> fp32 out
  gemm_mfma<ushort_t, float><<<dim3(DMODEL / 128, S_LEN / 128), blk, 0, stream>>>(ws_q, wo, out, S_LEN, DMODEL, DMODEL);
}

// Round 7
// 576.472 us; speedup vs baseline: 4.1747x; 2.9472x over previous
//
#include <hip/hip_runtime.h>

#define S_LEN 2048
#define NHQ 32
#define NKV 8
#define HD 64
#define DMODEL 2048   // NHQ*HD
#define DKV 512       // NKV*HD

typedef unsigned short ushort_t;
typedef unsigned int uint_t;

typedef __attribute__((ext_vector_type(8))) short bf16x8;
typedef __attribute__((ext_vector_type(4))) float f32x4;

__device__ __forceinline__ float b2f(ushort_t h) {
  union { uint_t u; float f; } v;
  v.u = ((uint_t)h) << 16;
  return v.f;
}
// round-to-nearest-even fp32 -> bf16
__device__ __forceinline__ ushort_t f2b(float f) {
  union { float f; uint_t u; } v;
  v.f = f;
  uint_t r = v.u + 0x7fffu + ((v.u >> 16) & 1u);
  return (ushort_t)(r >> 16);
}
__device__ __forceinline__ uint_t pack2(float lo, float hi) {
  return (uint_t)f2b(lo) | ((uint_t)f2b(hi) << 16);
}

__device__ __forceinline__ void stf(float* p, float v) { *p = v; }
__device__ __forceinline__ void stf(ushort_t* p, float v) { *p = f2b(v); }
__device__ __forceinline__ float ldf(const float* p) { return *p; }
__device__ __forceinline__ float ldf(const ushort_t* p) { return b2f(*p); }

union BF8 { uint4 v; ushort_t s[8]; };

// load 16 consecutive elements, convert to 16 bf16 packed in two uint4
__device__ __forceinline__ void load16cvt(const float* p, uint4& lo, uint4& hi) {
  const float4* q = (const float4*)p;
  float4 f0 = q[0], f1 = q[1], f2 = q[2], f3 = q[3];
  BF8 u0, u1;
  u0.s[0] = f2b(f0.x); u0.s[1] = f2b(f0.y); u0.s[2] = f2b(f0.z); u0.s[3] = f2b(f0.w);
  u0.s[4] = f2b(f1.x); u0.s[5] = f2b(f1.y); u0.s[6] = f2b(f1.z); u0.s[7] = f2b(f1.w);
  u1.s[0] = f2b(f2.x); u1.s[1] = f2b(f2.y); u1.s[2] = f2b(f2.z); u1.s[3] = f2b(f2.w);
  u1.s[4] = f2b(f3.x); u1.s[5] = f2b(f3.y); u1.s[6] = f2b(f3.z); u1.s[7] = f2b(f3.w);
  lo = u0.v; hi = u1.v;
}
__device__ __forceinline__ void load16cvt(const ushort_t* p, uint4& lo, uint4& hi) {
  lo = ((const uint4*)p)[0]; hi = ((const uint4*)p)[1];
}

// ---------------- MFMA GEMM (verified round 6, unchanged) ----------------
template<typename TA, typename TC>
__global__ __launch_bounds__(256) void gemm_mfma(const TA* __restrict__ A,
                                                 const float* __restrict__ B,
                                                 TC* __restrict__ C,
                                                 int M, int N, int K) {
  __shared__ ushort_t As[128][32];    // [m][k]
  __shared__ ushort_t BsT[128][40];   // [n][k]
  const int tid = threadIdx.x;
  const int lane = tid & 63;
  const int w = tid >> 6;
  const int wr = (w >> 1) * 64, wc = (w & 1) * 64;
  const int lm = lane & 15, kq = lane >> 4;
  const int tile_m = blockIdx.y * 128, tile_n = blockIdx.x * 128;

  const int am = tid >> 1, ak = (tid & 1) * 16;
  const int kp = tid >> 4, np2 = (tid & 15) * 2;

  f32x4 acc[4][4];
  #pragma unroll
  for (int i = 0; i < 4; ++i)
    #pragma unroll
    for (int j = 0; j < 4; ++j) acc[i][j] = {0.f, 0.f, 0.f, 0.f};

  for (int kt = 0; kt < K; kt += 32) {
    __syncthreads();
    uint4 lo, hi;
    load16cvt(A + (size_t)(tile_m + am) * K + kt + ak, lo, hi);
    *(uint4*)&As[am][ak]     = lo;
    *(uint4*)&As[am][ak + 8] = hi;
    const float* bp = B + (size_t)(kt + 2 * kp) * N + tile_n;
    #pragma unroll
    for (int j = 0; j < 4; ++j) {
      const int n = np2 + 32 * j;
      float2 r0 = *(const float2*)(bp + n);
      float2 r1 = *(const float2*)(bp + N + n);
      *(uint_t*)&BsT[n][2 * kp]     = pack2(r0.x, r1.x);
      *(uint_t*)&BsT[n + 1][2 * kp] = pack2(r0.y, r1.y);
    }
    __syncthreads();
    bf16x8 af[4], bfr[4];
    #pragma unroll
    for (int i = 0; i < 4; ++i) af[i]  = *(const bf16x8*)&As[wr + 16 * i + lm][kq * 8];
    #pragma unroll
    for (int j = 0; j < 4; ++j) bfr[j] = *(const bf16x8*)&BsT[wc + 16 * j + lm][kq * 8];
    #pragma unroll
    for (int i = 0; i < 4; ++i)
      #pragma unroll
      for (int j = 0; j < 4; ++j)
        acc[i][j] = __builtin_amdgcn_mfma_f32_16x16x32_bf16(af[i], bfr[j], acc[i][j], 0, 0, 0);
  }
  #pragma unroll
  for (int i = 0; i < 4; ++i)
    #pragma unroll
    for (int j = 0; j < 4; ++j)
      #pragma unroll
      for (int r = 0; r < 4; ++r) {
        const int row = tile_m + wr + 16 * i + kq * 4 + r;
        const int col = tile_n + wc + 16 * j + lm;
        stf(C + (size_t)row * N + col, acc[i][j][r]);
      }
}

// ---------------- RoPE (verified, unchanged) ----------------
template<typename T>
__global__ void rope_kernel(T* buf,
                            const float* __restrict__ cosT, const float* __restrict__ sinT,
                            int nh) {
  int idx = blockIdx.x * blockDim.x + threadIdx.x;
  int total = S_LEN * nh * 32;
  if (idx >= total) return;
  int d = idx & 31;
  int h = (idx >> 5) & (nh - 1);
  int r = idx / (nh * 32);
  size_t base = (size_t)r * nh * 64 + h * 64 + d;
  float x1 = ldf(buf + base);
  float x2 = ldf(buf + base + 32);
  float c = cosT[r * 64 + d];
  float s = sinT[r * 64 + d];
  stf(buf + base, x1 * c - x2 * s);
  stf(buf + base + 32, x1 * s + x2 * c);
}

// ---------------- K: fp32 [s][512] -> bf16 KB [hk][s][64] ----------------
__global__ void kb_kernel(const float* __restrict__ K, ushort_t* __restrict__ KB) {
  int gid = blockIdx.x * 256 + threadIdx.x;   // gid < 2048*512/4
  int flat = gid * 4;
  int s = flat >> 9;
  int c = flat & 511;
  int hk = c >> 6, d = c & 63;
  float4 v = *(const float4*)(K + flat);
  ushort_t* p = KB + (size_t)hk * S_LEN * HD + (size_t)s * HD + d;
  *(uint_t*)(p)     = pack2(v.x, v.y);
  *(uint_t*)(p + 2) = pack2(v.z, v.w);
}

// ---------------- V: fp32 [s][512] -> bf16 transposed VT [hk][64][s] ----------------
__global__ __launch_bounds__(256) void vt_kernel(const float* __restrict__ V,
                                                 ushort_t* __restrict__ VT) {
  __shared__ ushort_t T[64][66];
  const int tid = threadIdx.x;
  const int s0 = blockIdx.x * 64;
  const int hk = blockIdx.y;
  {
    const int s_l = tid >> 2, dp = (tid & 3) * 16;
    const float* p = V + (size_t)(s0 + s_l) * DKV + hk * HD + dp;
    float v[16];
    *(float4*)(v)      = *(const float4*)(p);
    *(float4*)(v + 4)  = *(const float4*)(p + 4);
    *(float4*)(v + 8)  = *(const float4*)(p + 8);
    *(float4*)(v + 12) = *(const float4*)(p + 12);
    #pragma unroll
    for (int j = 0; j < 16; ++j) T[dp + j][s_l] = f2b(v[j]);
  }
  __syncthreads();
  {
    const int d_l = tid >> 2, sp = (tid & 3) * 16;
    uint_t u[8];
    #pragma unroll
    for (int i = 0; i < 8; ++i) u[i] = *(const uint_t*)&T[d_l][sp + 2 * i];
    ushort_t* outp = VT + (size_t)hk * HD * S_LEN + (size_t)d_l * S_LEN + s0 + sp;
    *(uint4*)(outp)     = make_uint4(u[0], u[1], u[2], u[3]);
    *(uint4*)(outp + 8) = make_uint4(u[4], u[5], u[6], u[7]);
  }
}

// ---------------- MFMA flash attention, barrier-free ----------------
// One 64-lane wave per (head, 32-query group). Q bf16 [s][2048] (ws, in-place
// output), KB bf16 [hk][s][64], VT bf16 [hk][64][s].
// Sc^T = K.Q^T  (C-layout: col=lane&15=q, row=4*kq+r+16mt=key) -> per-lane
// softmax state (q=lm), reduction over registers + shfl_xor 16/32.
// out^T = V^T.P^T (A-frag rows of VT, B-frag rows of Ps[q][key]).
__global__ __launch_bounds__(64) void attn_mfma(const ushort_t* Q,
                                                const ushort_t* __restrict__ KB,
                                                const ushort_t* __restrict__ VT,
                                                ushort_t* O) {
  __shared__ ushort_t Ps[32][66];   // P^T [q_local][key], stride 66 (odd dwords)
  const int lane = threadIdx.x;
  const int lm = lane & 15, kq = lane >> 4;
  const int h  = blockIdx.x >> 6;
  const int q0 = (blockIdx.x & 63) * 32;
  const int hk = h >> 2;                      // N_REP = 4
  const ushort_t* KBh = KB + (size_t)hk * S_LEN * HD;
  const ushort_t* VTh = VT + (size_t)hk * HD * S_LEN;

  // hoisted Q B-frags: lane: q = q0+16nt+lm, d = 8kq+32kc
  bf16x8 bq[2][2];
  #pragma unroll
  for (int nt = 0; nt < 2; ++nt)
    #pragma unroll
    for (int kc = 0; kc < 2; ++kc)
      bq[nt][kc] = *(const bf16x8*)&Q[(size_t)(q0 + 16 * nt + lm) * DMODEL + h * HD + 8 * kq + 32 * kc];

  f32x4 Oa[4][2];   // out^T accum: dim = 16mt+4kq+r, q = 16nt+lm
  #pragma unroll
  for (int mt = 0; mt < 4; ++mt) { Oa[mt][0] = {0.f,0.f,0.f,0.f}; Oa[mt][1] = {0.f,0.f,0.f,0.f}; }
  float m[2] = {-1e30f, -1e30f}, l[2] = {0.f, 0.f};

  const int ntiles = (q0 + 31) / 64 + 1;
  for (int t = 0; t < ntiles; ++t) {
    const int base = t * 64;
    // ---- Sc^T = K.Q^T ----
    f32x4 sc[4][2];
    #pragma unroll
    for (int mt = 0; mt < 4; ++mt) { sc[mt][0] = {0.f,0.f,0.f,0.f}; sc[mt][1] = {0.f,0.f,0.f,0.f}; }
    #pragma unroll
    for (int kc = 0; kc < 2; ++kc) {
      bf16x8 ak[4];
      #pragma unroll
      for (int mt = 0; mt < 4; ++mt)
        ak[mt] = *(const bf16x8*)&KBh[(size_t)(base + 16 * mt + lm) * HD + 8 * kq + 32 * kc];
      #pragma unroll
      for (int mt = 0; mt < 4; ++mt)
        #pragma unroll
        for (int nt = 0; nt < 2; ++nt)
          sc[mt][nt] = __builtin_amdgcn_mfma_f32_16x16x32_bf16(ak[mt], bq[nt][kc], sc[mt][nt], 0, 0, 0);
    }
    const bool diag = (t == ntiles - 1);   // only the last tile straddles the causal boundary
    // ---- online softmax per q (= per lane, per nt) ----
    #pragma unroll
    for (int nt = 0; nt < 2; ++nt) {
      const int qg = q0 + 16 * nt + lm;
      #pragma unroll
      for (int mt = 0; mt < 4; ++mt)
        #pragma unroll
        for (int r = 0; r < 4; ++r) {
          float sv = sc[mt][nt][r] * 0.125f;           // 1/sqrt(64)
          if (diag && (base + 16 * mt + 4 * kq + r > qg)) sv = -1e9f;  // causal mask, like ref
          sc[mt][nt][r] = sv;
        }
      float mx = sc[0][nt][0];
      #pragma unroll
      for (int mt = 0; mt < 4; ++mt)
        #pragma unroll
        for (int r = 0; r < 4; ++r) mx = fmaxf(mx, sc[mt][nt][r]);
      mx = fmaxf(mx, __shfl_xor(mx, 16));
      mx = fmaxf(mx, __shfl_xor(mx, 32));
      const float mn = fmaxf(m[nt], mx);
      const float al = __expf(m[nt] - mn);
      m[nt] = mn;
      float sum = 0.f;
      #pragma unroll
      for (int mt = 0; mt < 4; ++mt)
        #pragma unroll
        for (int r = 0; r < 4; ++r) {
          float p = __expf(sc[mt][nt][r] - mn);
          sc[mt][nt][r] = p;
          sum += p;
        }
      sum += __shfl_xor(sum, 16);
      sum += __shfl_xor(sum, 32);
      l[nt] = l[nt] * al + sum;
      #pragma unroll
      for (int mt = 0; mt < 4; ++mt)
        #pragma unroll
        for (int r = 0; r < 4; ++r) Oa[mt][nt][r] *= al;
      // write P^T rows: Ps[q][key], b32-granular (2-way conflicts only)
      ushort_t* pw = &Ps[16 * nt + lm][4 * kq];
      #pragma unroll
      for (int mt = 0; mt < 4; ++mt) {
        *(uint_t*)(pw + 16 * mt)     = pack2(sc[mt][nt][0], sc[mt][nt][1]);
        *(uint_t*)(pw + 16 * mt + 2) = pack2(sc[mt][nt][2], sc[mt][nt][3]);
      }
    }
    // ---- out^T += V^T . P^T ----
    #pragma unroll
    for (int kc = 0; kc < 2; ++kc) {
      bf16x8 av[4], pb[2];
      #pragma unroll
      for (int mt = 0; mt < 4; ++mt)
        av[mt] = *(const bf16x8*)&VTh[(size_t)(16 * mt + lm) * S_LEN + base + 8 * kq + 32 * kc];
      #pragma unroll
      for (int nt = 0; nt < 2; ++nt) {
        const ushort_t* pr = &Ps[16 * nt + lm][8 * kq + 32 * kc];
        union { uint_t u[4]; bf16x8 v; } pu;
        pu.u[0] = *(const uint_t*)(pr);
        pu.u[1] = *(const uint_t*)(pr + 2);
        pu.u[2] = *(const uint_t*)(pr + 4);
        pu.u[3] = *(const uint_t*)(pr + 6);
        pb[nt] = pu.v;
      }
      #pragma unroll
      for (int mt = 0; mt < 4; ++mt)
        #pragma unroll
        for (int nt = 0; nt < 2; ++nt)
          Oa[mt][nt] = __builtin_amdgcn_mfma_f32_16x16x32_bf16(av[mt], pb[nt], Oa[mt][nt], 0, 0, 0);
    }
  }
  // ---- epilogue: O[q][h*64+dim] = out^T/l ----
  #pragma unroll
  for (int nt = 0; nt < 2; ++nt) {
    const float inv = 1.f / l[nt];
    ushort_t* orow = O + (size_t)(q0 + 16 * nt + lm) * DMODEL + h * HD + 4 * kq;
    #pragma unroll
    for (int mt = 0; mt < 4; ++mt) {
      *(uint_t*)(orow + 16 * mt)     = pack2(Oa[mt][nt][0] * inv, Oa[mt][nt][1] * inv);
      *(uint_t*)(orow + 16 * mt + 2) = pack2(Oa[mt][nt][2] * inv, Oa[mt][nt][3] * inv);
    }
  }
}

extern "C" void kernel_launch(void* const* d_in, const int* in_sizes, int n_in,
                              void* d_out, int out_size, void* d_ws, size_t ws_size,
                              hipStream_t stream) {
  const float* x    = (const float*)d_in[0];
  const float* cosT = (const float*)d_in[1];
  const float* sinT = (const float*)d_in[2];
  // d_in[3] = mask: causal -1e9, applied analytically (identical semantics)
  const float* wq   = (const float*)d_in[4];
  const float* wk   = (const float*)d_in[5];
  const float* wv   = (const float*)d_in[6];
  const float* wo   = (const float*)d_in[7];

  float* out   = (float*)d_out;                    // [S, 2048] fp32
  float* out_k = out + (size_t)S_LEN * DMODEL;     // new_k [S, 8, 64] fp32
  float* out_v = out_k + (size_t)S_LEN * DKV;      // new_v [S, 8, 64] fp32

  ushort_t* ws_q = (ushort_t*)d_ws;                          // q bf16 [S][2048] = 8 MB
  ushort_t* ws_kb = ws_q + (size_t)S_LEN * DMODEL;           // KB bf16 [8][S][64] = 2 MB
  ushort_t* ws_vt = ws_kb + (size_t)NKV * S_LEN * HD;        // VT bf16 [8][64][S] = 2 MB

  dim3 blk(256);
  // projections via MFMA (verified)
  gemm_mfma<float, ushort_t><<<dim3(DMODEL / 128, S_LEN / 128), blk, 0, stream>>>(x, wq, ws_q, S_LEN, DMODEL, DMODEL);
  gemm_mfma<float, float>   <<<dim3(DKV / 128,    S_LEN / 128), blk, 0, stream>>>(x, wk, out_k, S_LEN, DKV, DMODEL);
  gemm_mfma<float, float>   <<<dim3(DKV / 128,    S_LEN / 128), blk, 0, stream>>>(x, wv, out_v, S_LEN, DKV, DMODEL);
  // rope in-place (verified)
  rope_kernel<ushort_t><<<(S_LEN * NHQ * 32 + 255) / 256, 256, 0, stream>>>(ws_q, cosT, sinT, NHQ);
  rope_kernel<float>   <<<(S_LEN * NKV * 32 + 255) / 256, 256, 0, stream>>>(out_k, cosT, sinT, NKV);
  // bf16 K copy + bf16 transposed V copy for attention
  kb_kernel<<<(S_LEN * DKV / 4) / 256, 256, 0, stream>>>(out_k, ws_kb);
  vt_kernel<<<dim3(S_LEN / 64, NKV), blk, 0, stream>>>(out_v, ws_vt);
  // MFMA flash attention, in-place on q
  attn_mfma<<<NHQ * (S_LEN / 32), 64, 0, stream>>>(ws_q, ws_kb, ws_vt, ws_q);
  // output projection (verified)
  gemm_mfma<ushort_t, float><<<dim3(DMODEL / 128, S_LEN / 128), blk, 0, stream>>>(ws_q, wo, out, S_LEN, DMODEL, DMODEL);
}

// Round 8
// 315.746 us; speedup vs baseline: 7.6220x; 1.8257x over previous
//
#include <hip/hip_runtime.h>

#define S_LEN 2048
#define NHQ 32
#define NKV 8
#define HD 64
#define DMODEL 2048   // NHQ*HD
#define DKV 512       // NKV*HD

typedef unsigned short ushort_t;
typedef unsigned int uint_t;

typedef __attribute__((ext_vector_type(8))) short bf16x8;
typedef __attribute__((ext_vector_type(4))) float f32x4;

__device__ __forceinline__ float b2f(ushort_t h) {
  union { uint_t u; float f; } v;
  v.u = ((uint_t)h) << 16;
  return v.f;
}
// round-to-nearest-even fp32 -> bf16
__device__ __forceinline__ ushort_t f2b(float f) {
  union { float f; uint_t u; } v;
  v.f = f;
  uint_t r = v.u + 0x7fffu + ((v.u >> 16) & 1u);
  return (ushort_t)(r >> 16);
}
__device__ __forceinline__ uint_t pack2(float lo, float hi) {
  return (uint_t)f2b(lo) | ((uint_t)f2b(hi) << 16);
}

__device__ __forceinline__ void stf(float* p, float v) { *p = v; }
__device__ __forceinline__ void stf(ushort_t* p, float v) { *p = f2b(v); }
__device__ __forceinline__ float ldf(const float* p) { return *p; }
__device__ __forceinline__ float ldf(const ushort_t* p) { return b2f(*p); }

union BF8 { uint4 v; ushort_t s[8]; };

__device__ __forceinline__ void load16cvt(const float* p, uint4& lo, uint4& hi) {
  const float4* q = (const float4*)p;
  float4 f0 = q[0], f1 = q[1], f2 = q[2], f3 = q[3];
  BF8 u0, u1;
  u0.s[0] = f2b(f0.x); u0.s[1] = f2b(f0.y); u0.s[2] = f2b(f0.z); u0.s[3] = f2b(f0.w);
  u0.s[4] = f2b(f1.x); u0.s[5] = f2b(f1.y); u0.s[6] = f2b(f1.z); u0.s[7] = f2b(f1.w);
  u1.s[0] = f2b(f2.x); u1.s[1] = f2b(f2.y); u1.s[2] = f2b(f2.z); u1.s[3] = f2b(f2.w);
  u1.s[4] = f2b(f3.x); u1.s[5] = f2b(f3.y); u1.s[6] = f2b(f3.z); u1.s[7] = f2b(f3.w);
  lo = u0.v; hi = u1.v;
}
__device__ __forceinline__ void load16cvt(const ushort_t* p, uint4& lo, uint4& hi) {
  lo = ((const uint4*)p)[0]; hi = ((const uint4*)p)[1];
}

// ==================== FAST PATH (ws >= 24 MB) ====================

// x fp32 -> bf16 flat (8 elems/thread)
__global__ void xb_kernel(const float* __restrict__ X, ushort_t* __restrict__ XB) {
  int i = (blockIdx.x * 256 + threadIdx.x) * 8;
  uint4 lo, hi;
  load16cvt(X + i, lo, hi);
  // load16cvt gives 16; we only need 8 -> do it directly instead:
  // (kept simple: write only lo's 8)
  float4 a = *(const float4*)(X + i);
  float4 b = *(const float4*)(X + i + 4);
  BF8 u;
  u.s[0] = f2b(a.x); u.s[1] = f2b(a.y); u.s[2] = f2b(a.z); u.s[3] = f2b(a.w);
  u.s[4] = f2b(b.x); u.s[5] = f2b(b.y); u.s[6] = f2b(b.z); u.s[7] = f2b(b.w);
  *(uint4*)(XB + i) = u.v;
}

// W [K=2048][N] fp32 -> WT [N][K] bf16 (64x64 LDS tiles; vt_kernel pattern)
__global__ __launch_bounds__(256) void wT_kernel(const float* __restrict__ W,
                                                 ushort_t* __restrict__ WT,
                                                 int K, int N) {
  __shared__ ushort_t T[64][66];
  const int tid = threadIdx.x;
  const int r0 = blockIdx.x * 64;   // K dim
  const int c0 = blockIdx.y * 64;   // N dim
  {
    const int rl = tid >> 2, cp = (tid & 3) * 16;
    const float* p = W + (size_t)(r0 + rl) * N + c0 + cp;
    float v[16];
    *(float4*)(v)      = *(const float4*)(p);
    *(float4*)(v + 4)  = *(const float4*)(p + 4);
    *(float4*)(v + 8)  = *(const float4*)(p + 8);
    *(float4*)(v + 12) = *(const float4*)(p + 12);
    #pragma unroll
    for (int j = 0; j < 16; ++j) T[cp + j][rl] = f2b(v[j]);
  }
  __syncthreads();
  {
    const int cl = tid >> 2, rp = (tid & 3) * 16;
    uint_t u[8];
    #pragma unroll
    for (int i = 0; i < 8; ++i) u[i] = *(const uint_t*)&T[cl][rp + 2 * i];
    ushort_t* outp = WT + (size_t)(c0 + cl) * K + r0 + rp;
    *(uint4*)(outp)     = make_uint4(u[0], u[1], u[2], u[3]);
    *(uint4*)(outp + 8) = make_uint4(u[4], u[5], u[6], u[7]);
  }
}

// Shared GEMM core: A bf16 [M][K] row-major, BT bf16 [N][K] row-major.
// 128x128 tile, BK=32, 4 waves, 4x4 16x16x32 MFMA per wave. LDS stride 40.
__device__ __forceinline__ void gemm_core(const ushort_t* __restrict__ A,
                                          const ushort_t* __restrict__ BT,
                                          int K, int tile_m, int tile_n,
                                          f32x4 (&acc)[4][4],
                                          ushort_t (*As)[40], ushort_t (*Bs)[40]) {
  const int tid = threadIdx.x;
  const int lane = tid & 63;
  const int w = tid >> 6;
  const int wr = (w >> 1) * 64, wc = (w & 1) * 64;
  const int lm = lane & 15, kq = lane >> 4;
  const int sr = tid >> 1, sk = (tid & 1) * 16;

  #pragma unroll
  for (int i = 0; i < 4; ++i)
    #pragma unroll
    for (int j = 0; j < 4; ++j) acc[i][j] = {0.f, 0.f, 0.f, 0.f};

  const ushort_t* ap = A  + (size_t)(tile_m + sr) * K + sk;
  const ushort_t* bp = BT + (size_t)(tile_n + sr) * K + sk;

  for (int kt = 0; kt < K; kt += 32) {
    __syncthreads();
    uint4 a0 = ((const uint4*)(ap + kt))[0], a1 = ((const uint4*)(ap + kt))[1];
    uint4 b0 = ((const uint4*)(bp + kt))[0], b1 = ((const uint4*)(bp + kt))[1];
    *(uint4*)&As[sr][sk]     = a0;
    *(uint4*)&As[sr][sk + 8] = a1;
    *(uint4*)&Bs[sr][sk]     = b0;
    *(uint4*)&Bs[sr][sk + 8] = b1;
    __syncthreads();
    bf16x8 af[4], bfr[4];
    #pragma unroll
    for (int i = 0; i < 4; ++i) af[i]  = *(const bf16x8*)&As[wr + 16 * i + lm][kq * 8];
    #pragma unroll
    for (int j = 0; j < 4; ++j) bfr[j] = *(const bf16x8*)&Bs[wc + 16 * j + lm][kq * 8];
    #pragma unroll
    for (int i = 0; i < 4; ++i)
      #pragma unroll
      for (int j = 0; j < 4; ++j)
        acc[i][j] = __builtin_amdgcn_mfma_f32_16x16x32_bf16(af[i], bfr[j], acc[i][j], 0, 0, 0);
  }
}

// Fused q/k/v projection: BT = [wqT|wkT|wvT] (N=3072). Split epilogue:
// col<2048 -> q bf16; col<2560 -> out_k fp32; else out_v fp32.
__global__ __launch_bounds__(256) void gemm_proj(const ushort_t* __restrict__ A,
                                                 const ushort_t* __restrict__ BT,
                                                 ushort_t* __restrict__ Qo,
                                                 float* __restrict__ Ko,
                                                 float* __restrict__ Vo) {
  __shared__ ushort_t As[128][40];
  __shared__ ushort_t Bs[128][40];
  const int lane = threadIdx.x & 63;
  const int w = threadIdx.x >> 6;
  const int wr = (w >> 1) * 64, wc = (w & 1) * 64;
  const int lm = lane & 15, kq = lane >> 4;
  const int tile_m = blockIdx.y * 128, tile_n = blockIdx.x * 128;
  f32x4 acc[4][4];
  gemm_core(A, BT, DMODEL, tile_m, tile_n, acc, As, Bs);
  #pragma unroll
  for (int i = 0; i < 4; ++i)
    #pragma unroll
    for (int j = 0; j < 4; ++j)
      #pragma unroll
      for (int r = 0; r < 4; ++r) {
        const int row = tile_m + wr + 16 * i + kq * 4 + r;
        const int col = tile_n + wc + 16 * j + lm;
        const float v = acc[i][j][r];
        if (col < 2048)      Qo[(size_t)row * DMODEL + col] = f2b(v);
        else if (col < 2560) Ko[(size_t)row * DKV + col - 2048] = v;
        else                 Vo[(size_t)row * DKV + col - 2560] = v;
      }
}

// Plain GEMM: C fp32 [M][N], N = DMODEL (final projection)
__global__ __launch_bounds__(256) void gemm_out(const ushort_t* __restrict__ A,
                                                const ushort_t* __restrict__ BT,
                                                float* __restrict__ C) {
  __shared__ ushort_t As[128][40];
  __shared__ ushort_t Bs[128][40];
  const int lane = threadIdx.x & 63;
  const int w = threadIdx.x >> 6;
  const int wr = (w >> 1) * 64, wc = (w & 1) * 64;
  const int lm = lane & 15, kq = lane >> 4;
  const int tile_m = blockIdx.y * 128, tile_n = blockIdx.x * 128;
  f32x4 acc[4][4];
  gemm_core(A, BT, DMODEL, tile_m, tile_n, acc, As, Bs);
  #pragma unroll
  for (int i = 0; i < 4; ++i)
    #pragma unroll
    for (int j = 0; j < 4; ++j)
      #pragma unroll
      for (int r = 0; r < 4; ++r) {
        const int row = tile_m + wr + 16 * i + kq * 4 + r;
        const int col = tile_n + wc + 16 * j + lm;
        C[(size_t)row * DMODEL + col] = acc[i][j][r];
      }
}

// Fused rope(K) in-place fp32 + bf16 KB [hk][s][64] copy.
__global__ void rope_kb_kernel(float* Kio, ushort_t* __restrict__ KB,
                               const float* __restrict__ cosT, const float* __restrict__ sinT) {
  int idx = blockIdx.x * 256 + threadIdx.x;   // < S*8*32
  int d = idx & 31;
  int hk = (idx >> 5) & 7;
  int s = idx >> 8;
  float* p = Kio + (size_t)s * DKV + hk * HD + d;
  float x1 = p[0], x2 = p[32];
  float c = cosT[s * 64 + d], sn = sinT[s * 64 + d];
  float n1 = x1 * c - x2 * sn;
  float n2 = x1 * sn + x2 * c;
  p[0] = n1; p[32] = n2;
  ushort_t* kb = KB + (size_t)hk * S_LEN * HD + (size_t)s * HD + d;
  kb[0] = f2b(n1); kb[32] = f2b(n2);
}

// V: fp32 [s][512] -> bf16 transposed VT [hk][64][s]   (verified round 7)
__global__ __launch_bounds__(256) void vt_kernel(const float* __restrict__ V,
                                                 ushort_t* __restrict__ VT) {
  __shared__ ushort_t T[64][66];
  const int tid = threadIdx.x;
  const int s0 = blockIdx.x * 64;
  const int hk = blockIdx.y;
  {
    const int s_l = tid >> 2, dp = (tid & 3) * 16;
    const float* p = V + (size_t)(s0 + s_l) * DKV + hk * HD + dp;
    float v[16];
    *(float4*)(v)      = *(const float4*)(p);
    *(float4*)(v + 4)  = *(const float4*)(p + 4);
    *(float4*)(v + 8)  = *(const float4*)(p + 8);
    *(float4*)(v + 12) = *(const float4*)(p + 12);
    #pragma unroll
    for (int j = 0; j < 16; ++j) T[dp + j][s_l] = f2b(v[j]);
  }
  __syncthreads();
  {
    const int d_l = tid >> 2, sp = (tid & 3) * 16;
    uint_t u[8];
    #pragma unroll
    for (int i = 0; i < 8; ++i) u[i] = *(const uint_t*)&T[d_l][sp + 2 * i];
    ushort_t* outp = VT + (size_t)hk * HD * S_LEN + (size_t)d_l * S_LEN + s0 + sp;
    *(uint4*)(outp)     = make_uint4(u[0], u[1], u[2], u[3]);
    *(uint4*)(outp + 8) = make_uint4(u[4], u[5], u[6], u[7]);
  }
}

// MFMA flash attention v2: 128-thread block = 2 independent waves handling
// paired query groups (g, 63-g) -> uniform 33 key-tiles per block.
// RoPE applied to Q in-register at fragment load (kc=0/1 chunks are the
// rope pair (d, d+32)). Structure otherwise = verified round-7 attn_mfma.
__global__ __launch_bounds__(128) void attn_mfma2(const ushort_t* Q,
                                                  const ushort_t* __restrict__ KB,
                                                  const ushort_t* __restrict__ VT,
                                                  const float* __restrict__ cosT,
                                                  const float* __restrict__ sinT,
                                                  ushort_t* O) {
  __shared__ ushort_t Ps[2][32][66];
  const int wv = threadIdx.x >> 6;
  const int lane = threadIdx.x & 63;
  const int lm = lane & 15, kq = lane >> 4;
  const int h = blockIdx.x >> 5;
  const int pr_ = blockIdx.x & 31;
  const int g = wv ? (63 - pr_) : pr_;
  const int q0 = g * 32;
  const int hk = h >> 2;
  const ushort_t* KBh = KB + (size_t)hk * S_LEN * HD;
  const ushort_t* VTh = VT + (size_t)hk * HD * S_LEN;

  // hoisted Q B-frags with in-register RoPE: lane: q = q0+16nt+lm, d = 8kq (+32)
  bf16x8 bq[2][2];
  #pragma unroll
  for (int nt = 0; nt < 2; ++nt) {
    const int row = q0 + 16 * nt + lm;
    const ushort_t* qp = Q + (size_t)row * DMODEL + h * HD + 8 * kq;
    bf16x8 x1v = *(const bf16x8*)qp;
    bf16x8 x2v = *(const bf16x8*)(qp + 32);
    const float* cp = cosT + row * 64 + 8 * kq;
    const float* sp = sinT + row * 64 + 8 * kq;
    float c[8], s[8];
    *(float4*)(c)     = *(const float4*)(cp);
    *(float4*)(c + 4) = *(const float4*)(cp + 4);
    *(float4*)(s)     = *(const float4*)(sp);
    *(float4*)(s + 4) = *(const float4*)(sp + 4);
    BF8 o1, o2;
    #pragma unroll
    for (int j = 0; j < 8; ++j) {
      float x1 = b2f((ushort_t)x1v[j]);
      float x2 = b2f((ushort_t)x2v[j]);
      o1.s[j] = f2b(x1 * c[j] - x2 * s[j]);
      o2.s[j] = f2b(x1 * s[j] + x2 * c[j]);
    }
    bq[nt][0] = *(const bf16x8*)&o1;
    bq[nt][1] = *(const bf16x8*)&o2;
  }

  f32x4 Oa[4][2];
  #pragma unroll
  for (int mt = 0; mt < 4; ++mt) { Oa[mt][0] = {0.f,0.f,0.f,0.f}; Oa[mt][1] = {0.f,0.f,0.f,0.f}; }
  float m[2] = {-1e30f, -1e30f}, l[2] = {0.f, 0.f};

  const int ntiles = (q0 + 31) / 64 + 1;
  for (int t = 0; t < ntiles; ++t) {
    const int base = t * 64;
    f32x4 sc[4][2];
    #pragma unroll
    for (int mt = 0; mt < 4; ++mt) { sc[mt][0] = {0.f,0.f,0.f,0.f}; sc[mt][1] = {0.f,0.f,0.f,0.f}; }
    #pragma unroll
    for (int kc = 0; kc < 2; ++kc) {
      bf16x8 ak[4];
      #pragma unroll
      for (int mt = 0; mt < 4; ++mt)
        ak[mt] = *(const bf16x8*)&KBh[(size_t)(base + 16 * mt + lm) * HD + 8 * kq + 32 * kc];
      #pragma unroll
      for (int mt = 0; mt < 4; ++mt)
        #pragma unroll
        for (int nt = 0; nt < 2; ++nt)
          sc[mt][nt] = __builtin_amdgcn_mfma_f32_16x16x32_bf16(ak[mt], bq[nt][kc], sc[mt][nt], 0, 0, 0);
    }
    const bool diag = (t == ntiles - 1);
    #pragma unroll
    for (int nt = 0; nt < 2; ++nt) {
      const int qg = q0 + 16 * nt + lm;
      #pragma unroll
      for (int mt = 0; mt < 4; ++mt)
        #pragma unroll
        for (int r = 0; r < 4; ++r) {
          float sv = sc[mt][nt][r] * 0.125f;
          if (diag && (base + 16 * mt + 4 * kq + r > qg)) sv = -1e9f;
          sc[mt][nt][r] = sv;
        }
      float mx = sc[0][nt][0];
      #pragma unroll
      for (int mt = 0; mt < 4; ++mt)
        #pragma unroll
        for (int r = 0; r < 4; ++r) mx = fmaxf(mx, sc[mt][nt][r]);
      mx = fmaxf(mx, __shfl_xor(mx, 16));
      mx = fmaxf(mx, __shfl_xor(mx, 32));
      const float mn = fmaxf(m[nt], mx);
      const float al = __expf(m[nt] - mn);
      m[nt] = mn;
      float sum = 0.f;
      #pragma unroll
      for (int mt = 0; mt < 4; ++mt)
        #pragma unroll
        for (int r = 0; r < 4; ++r) {
          float p = __expf(sc[mt][nt][r] - mn);
          sc[mt][nt][r] = p;
          sum += p;
        }
      sum += __shfl_xor(sum, 16);
      sum += __shfl_xor(sum, 32);
      l[nt] = l[nt] * al + sum;
      #pragma unroll
      for (int mt = 0; mt < 4; ++mt)
        #pragma unroll
        for (int r = 0; r < 4; ++r) Oa[mt][nt][r] *= al;
      ushort_t* pw = &Ps[wv][16 * nt + lm][4 * kq];
      #pragma unroll
      for (int mt = 0; mt < 4; ++mt) {
        *(uint_t*)(pw + 16 * mt)     = pack2(sc[mt][nt][0], sc[mt][nt][1]);
        *(uint_t*)(pw + 16 * mt + 2) = pack2(sc[mt][nt][2], sc[mt][nt][3]);
      }
    }
    #pragma unroll
    for (int kc = 0; kc < 2; ++kc) {
      bf16x8 av[4], pb[2];
      #pragma unroll
      for (int mt = 0; mt < 4; ++mt)
        av[mt] = *(const bf16x8*)&VTh[(size_t)(16 * mt + lm) * S_LEN + base + 8 * kq + 32 * kc];
      #pragma unroll
      for (int nt = 0; nt < 2; ++nt) {
        const ushort_t* prr = &Ps[wv][16 * nt + lm][8 * kq + 32 * kc];
        union { uint_t u[4]; bf16x8 v; } pu;
        pu.u[0] = *(const uint_t*)(prr);
        pu.u[1] = *(const uint_t*)(prr + 2);
        pu.u[2] = *(const uint_t*)(prr + 4);
        pu.u[3] = *(const uint_t*)(prr + 6);
        pb[nt] = pu.v;
      }
      #pragma unroll
      for (int mt = 0; mt < 4; ++mt)
        #pragma unroll
        for (int nt = 0; nt < 2; ++nt)
          Oa[mt][nt] = __builtin_amdgcn_mfma_f32_16x16x32_bf16(av[mt], pb[nt], Oa[mt][nt], 0, 0, 0);
    }
  }
  #pragma unroll
  for (int nt = 0; nt < 2; ++nt) {
    const float inv = 1.f / l[nt];
    ushort_t* orow = O + (size_t)(q0 + 16 * nt + lm) * DMODEL + h * HD + 4 * kq;
    #pragma unroll
    for (int mt = 0; mt < 4; ++mt) {
      *(uint_t*)(orow + 16 * mt)     = pack2(Oa[mt][nt][0] * inv, Oa[mt][nt][1] * inv);
      *(uint_t*)(orow + 16 * mt + 2) = pack2(Oa[mt][nt][2] * inv, Oa[mt][nt][3] * inv);
    }
  }
}

// ==================== FALLBACK PATH (verified round 7) ====================

template<typename TA, typename TC>
__global__ __launch_bounds__(256) void gemm_mfma_old(const TA* __restrict__ A,
                                                     const float* __restrict__ B,
                                                     TC* __restrict__ C,
                                                     int M, int N, int K) {
  __shared__ ushort_t As[128][32];
  __shared__ ushort_t BsT[128][40];
  const int tid = threadIdx.x;
  const int lane = tid & 63;
  const int w = tid >> 6;
  const int wr = (w >> 1) * 64, wc = (w & 1) * 64;
  const int lm = lane & 15, kq = lane >> 4;
  const int tile_m = blockIdx.y * 128, tile_n = blockIdx.x * 128;
  const int am = tid >> 1, ak = (tid & 1) * 16;
  const int kp = tid >> 4, np2 = (tid & 15) * 2;
  f32x4 acc[4][4];
  #pragma unroll
  for (int i = 0; i < 4; ++i)
    #pragma unroll
    for (int j = 0; j < 4; ++j) acc[i][j] = {0.f, 0.f, 0.f, 0.f};
  for (int kt = 0; kt < K; kt += 32) {
    __syncthreads();
    uint4 lo, hi;
    load16cvt(A + (size_t)(tile_m + am) * K + kt + ak, lo, hi);
    *(uint4*)&As[am][ak]     = lo;
    *(uint4*)&As[am][ak + 8] = hi;
    const float* bp = B + (size_t)(kt + 2 * kp) * N + tile_n;
    #pragma unroll
    for (int j = 0; j < 4; ++j) {
      const int n = np2 + 32 * j;
      float2 r0 = *(const float2*)(bp + n);
      float2 r1 = *(const float2*)(bp + N + n);
      *(uint_t*)&BsT[n][2 * kp]     = pack2(r0.x, r1.x);
      *(uint_t*)&BsT[n + 1][2 * kp] = pack2(r0.y, r1.y);
    }
    __syncthreads();
    bf16x8 af[4], bfr[4];
    #pragma unroll
    for (int i = 0; i < 4; ++i) af[i]  = *(const bf16x8*)&As[wr + 16 * i + lm][kq * 8];
    #pragma unroll
    for (int j = 0; j < 4; ++j) bfr[j] = *(const bf16x8*)&BsT[wc + 16 * j + lm][kq * 8];
    #pragma unroll
    for (int i = 0; i < 4; ++i)
      #pragma unroll
      for (int j = 0; j < 4; ++j)
        acc[i][j] = __builtin_amdgcn_mfma_f32_16x16x32_bf16(af[i], bfr[j], acc[i][j], 0, 0, 0);
  }
  #pragma unroll
  for (int i = 0; i < 4; ++i)
    #pragma unroll
    for (int j = 0; j < 4; ++j)
      #pragma unroll
      for (int r = 0; r < 4; ++r) {
        const int row = tile_m + wr + 16 * i + kq * 4 + r;
        const int col = tile_n + wc + 16 * j + lm;
        stf(C + (size_t)row * N + col, acc[i][j][r]);
      }
}

template<typename T>
__global__ void rope_kernel(T* buf, const float* __restrict__ cosT,
                            const float* __restrict__ sinT, int nh) {
  int idx = blockIdx.x * blockDim.x + threadIdx.x;
  int total = S_LEN * nh * 32;
  if (idx >= total) return;
  int d = idx & 31;
  int h = (idx >> 5) & (nh - 1);
  int r = idx / (nh * 32);
  size_t base = (size_t)r * nh * 64 + h * 64 + d;
  float x1 = ldf(buf + base);
  float x2 = ldf(buf + base + 32);
  float c = cosT[r * 64 + d];
  float s = sinT[r * 64 + d];
  stf(buf + base, x1 * c - x2 * s);
  stf(buf + base + 32, x1 * s + x2 * c);
}

__global__ void kb_kernel(const float* __restrict__ K, ushort_t* __restrict__ KB) {
  int gid = blockIdx.x * 256 + threadIdx.x;
  int flat = gid * 4;
  int s = flat >> 9;
  int c = flat & 511;
  int hk = c >> 6, d = c & 63;
  float4 v = *(const float4*)(K + flat);
  ushort_t* p = KB + (size_t)hk * S_LEN * HD + (size_t)s * HD + d;
  *(uint_t*)(p)     = pack2(v.x, v.y);
  *(uint_t*)(p + 2) = pack2(v.z, v.w);
}

__global__ __launch_bounds__(64) void attn_mfma_old(const ushort_t* Q,
                                                    const ushort_t* __restrict__ KB,
                                                    const ushort_t* __restrict__ VT,
                                                    ushort_t* O) {
  __shared__ ushort_t Ps[32][66];
  const int lane = threadIdx.x;
  const int lm = lane & 15, kq = lane >> 4;
  const int h  = blockIdx.x >> 6;
  const int q0 = (blockIdx.x & 63) * 32;
  const int hk = h >> 2;
  const ushort_t* KBh = KB + (size_t)hk * S_LEN * HD;
  const ushort_t* VTh = VT + (size_t)hk * HD * S_LEN;
  bf16x8 bq[2][2];
  #pragma unroll
  for (int nt = 0; nt < 2; ++nt)
    #pragma unroll
    for (int kc = 0; kc < 2; ++kc)
      bq[nt][kc] = *(const bf16x8*)&Q[(size_t)(q0 + 16 * nt + lm) * DMODEL + h * HD + 8 * kq + 32 * kc];
  f32x4 Oa[4][2];
  #pragma unroll
  for (int mt = 0; mt < 4; ++mt) { Oa[mt][0] = {0.f,0.f,0.f,0.f}; Oa[mt][1] = {0.f,0.f,0.f,0.f}; }
  float m[2] = {-1e30f, -1e30f}, l[2] = {0.f, 0.f};
  const int ntiles = (q0 + 31) / 64 + 1;
  for (int t = 0; t < ntiles; ++t) {
    const int base = t * 64;
    f32x4 sc[4][2];
    #pragma unroll
    for (int mt = 0; mt < 4; ++mt) { sc[mt][0] = {0.f,0.f,0.f,0.f}; sc[mt][1] = {0.f,0.f,0.f,0.f}; }
    #pragma unroll
    for (int kc = 0; kc < 2; ++kc) {
      bf16x8 ak[4];
      #pragma unroll
      for (int mt = 0; mt < 4; ++mt)
        ak[mt] = *(const bf16x8*)&KBh[(size_t)(base + 16 * mt + lm) * HD + 8 * kq + 32 * kc];
      #pragma unroll
      for (int mt = 0; mt < 4; ++mt)
        #pragma unroll
        for (int nt = 0; nt < 2; ++nt)
          sc[mt][nt] = __builtin_amdgcn_mfma_f32_16x16x32_bf16(ak[mt], bq[nt][kc], sc[mt][nt], 0, 0, 0);
    }
    const bool diag = (t == ntiles - 1);
    #pragma unroll
    for (int nt = 0; nt < 2; ++nt) {
      const int qg = q0 + 16 * nt + lm;
      #pragma unroll
      for (int mt = 0; mt < 4; ++mt)
        #pragma unroll
        for (int r = 0; r < 4; ++r) {
          float sv = sc[mt][nt][r] * 0.125f;
          if (diag && (base + 16 * mt + 4 * kq + r > qg)) sv = -1e9f;
          sc[mt][nt][r] = sv;
        }
      float mx = sc[0][nt][0];
      #pragma unroll
      for (int mt = 0; mt < 4; ++mt)
        #pragma unroll
        for (int r = 0; r < 4; ++r) mx = fmaxf(mx, sc[mt][nt][r]);
      mx = fmaxf(mx, __shfl_xor(mx, 16));
      mx = fmaxf(mx, __shfl_xor(mx, 32));
      const float mn = fmaxf(m[nt], mx);
      const float al = __expf(m[nt] - mn);
      m[nt] = mn;
      float sum = 0.f;
      #pragma unroll
      for (int mt = 0; mt < 4; ++mt)
        #pragma unroll
        for (int r = 0; r < 4; ++r) {
          float p = __expf(sc[mt][nt][r] - mn);
          sc[mt][nt][r] = p;
          sum += p;
        }
      sum += __shfl_xor(sum, 16);
      sum += __shfl_xor(sum, 32);
      l[nt] = l[nt] * al + sum;
      #pragma unroll
      for (int mt = 0; mt < 4; ++mt)
        #pragma unroll
        for (int r = 0; r < 4; ++r) Oa[mt][nt][r] *= al;
      ushort_t* pw = &Ps[16 * nt + lm][4 * kq];
      #pragma unroll
      for (int mt = 0; mt < 4; ++mt) {
        *(uint_t*)(pw + 16 * mt)     = pack2(sc[mt][nt][0], sc[mt][nt][1]);
        *(uint_t*)(pw + 16 * mt + 2) = pack2(sc[mt][nt][2], sc[mt][nt][3]);
      }
    }
    #pragma unroll
    for (int kc = 0; kc < 2; ++kc) {
      bf16x8 av[4], pb[2];
      #pragma unroll
      for (int mt = 0; mt < 4; ++mt)
        av[mt] = *(const bf16x8*)&VTh[(size_t)(16 * mt + lm) * S_LEN + base + 8 * kq + 32 * kc];
      #pragma unroll
      for (int nt = 0; nt < 2; ++nt) {
        const ushort_t* prr = &Ps[16 * nt + lm][8 * kq + 32 * kc];
        union { uint_t u[4]; bf16x8 v; } pu;
        pu.u[0] = *(const uint_t*)(prr);
        pu.u[1] = *(const uint_t*)(prr + 2);
        pu.u[2] = *(const uint_t*)(prr + 4);
        pu.u[3] = *(const uint_t*)(prr + 6);
        pb[nt] = pu.v;
      }
      #pragma unroll
      for (int mt = 0; mt < 4; ++mt)
        #pragma unroll
        for (int nt = 0; nt < 2; ++nt)
          Oa[mt][nt] = __builtin_amdgcn_mfma_f32_16x16x32_bf16(av[mt], pb[nt], Oa[mt][nt], 0, 0, 0);
    }
  }
  #pragma unroll
  for (int nt = 0; nt < 2; ++nt) {
    const float inv = 1.f / l[nt];
    ushort_t* orow = O + (size_t)(q0 + 16 * nt + lm) * DMODEL + h * HD + 4 * kq;
    #pragma unroll
    for (int mt = 0; mt < 4; ++mt) {
      *(uint_t*)(orow + 16 * mt)     = pack2(Oa[mt][nt][0] * inv, Oa[mt][nt][1] * inv);
      *(uint_t*)(orow + 16 * mt + 2) = pack2(Oa[mt][nt][2] * inv, Oa[mt][nt][3] * inv);
    }
  }
}

extern "C" void kernel_launch(void* const* d_in, const int* in_sizes, int n_in,
                              void* d_out, int out_size, void* d_ws, size_t ws_size,
                              hipStream_t stream) {
  const float* x    = (const float*)d_in[0];
  const float* cosT = (const float*)d_in[1];
  const float* sinT = (const float*)d_in[2];
  // d_in[3] = mask: causal -1e9, applied analytically (identical semantics)
  const float* wq   = (const float*)d_in[4];
  const float* wk   = (const float*)d_in[5];
  const float* wv   = (const float*)d_in[6];
  const float* wo   = (const float*)d_in[7];

  float* out   = (float*)d_out;                    // [S, 2048] fp32
  float* out_k = out + (size_t)S_LEN * DMODEL;     // new_k [S, 8, 64] fp32
  float* out_v = out_k + (size_t)S_LEN * DKV;      // new_v [S, 8, 64] fp32

  dim3 blk(256);
  const size_t MB = 1024 * 1024;

  if (ws_size >= 24 * MB) {
    // ---- fast path ----
    ushort_t* ws   = (ushort_t*)d_ws;
    ushort_t* wqT  = ws;                                  // [0,8M)  wqT [2048][2048] bf16; later woT
    ushort_t* wkT  = ws + 4 * MB;                         // [8,10M) wkT [512][2048]
    // wvT contiguous after wkT -> fused BT = [wqT|wkT|wvT] = [3072][2048]
    ushort_t* ws_q = ws + 6 * MB;                         // [12,20M) q bf16 [S][2048]
    ushort_t* ws_kb = ws + 10 * MB;                       // [20,22M) KB bf16 [8][S][64]
    ushort_t* ws_vt = ws + 11 * MB;                       // [22,24M) VT bf16 [8][64][S]
    ushort_t* xb   = (ushort_t*)out;                      // scratch in dead out region (8 MB of 16)

    // prework: bf16 conversions + weight transposes
    xb_kernel<<<(S_LEN * DMODEL / 8) / 256, 256, 0, stream>>>(x, xb);
    wT_kernel<<<dim3(32, 32), blk, 0, stream>>>(wq, wqT, DMODEL, DMODEL);
    wT_kernel<<<dim3(32, 8),  blk, 0, stream>>>(wk, wkT, DMODEL, DKV);
    wT_kernel<<<dim3(32, 8),  blk, 0, stream>>>(wv, wkT + (size_t)DKV * DMODEL, DMODEL, DKV);
    // fused q/k/v projection (N = 3072)
    gemm_proj<<<dim3(3072 / 128, S_LEN / 128), blk, 0, stream>>>(xb, wqT, ws_q, out_k, out_v);
    // wo^T overwrites wqT (dead after gemm_proj); xb dead after gemm_proj too
    wT_kernel<<<dim3(32, 32), blk, 0, stream>>>(wo, wqT, DMODEL, DMODEL);
    // rope(K) in-place + bf16 KB; V transpose
    rope_kb_kernel<<<(S_LEN * NKV * 32) / 256, 256, 0, stream>>>(out_k, ws_kb, cosT, sinT);
    vt_kernel<<<dim3(S_LEN / 64, NKV), blk, 0, stream>>>(out_v, ws_vt);
    // attention (rope-on-Q fused, paired groups), in-place on q
    attn_mfma2<<<NHQ * 32, 128, 0, stream>>>(ws_q, ws_kb, ws_vt, cosT, sinT, ws_q);
    // final projection
    gemm_out<<<dim3(DMODEL / 128, S_LEN / 128), blk, 0, stream>>>(ws_q, wqT, out);
  } else {
    // ---- verified round-7 fallback (12 MB ws) ----
    ushort_t* ws_q  = (ushort_t*)d_ws;
    ushort_t* ws_kb = ws_q + (size_t)S_LEN * DMODEL;
    ushort_t* ws_vt = ws_kb + (size_t)NKV * S_LEN * HD;
    gemm_mfma_old<float, ushort_t><<<dim3(DMODEL / 128, S_LEN / 128), blk, 0, stream>>>(x, wq, ws_q, S_LEN, DMODEL, DMODEL);
    gemm_mfma_old<float, float>   <<<dim3(DKV / 128,    S_LEN / 128), blk, 0, stream>>>(x, wk, out_k, S_LEN, DKV, DMODEL);
    gemm_mfma_old<float, float>   <<<dim3(DKV / 128,    S_LEN / 128), blk, 0, stream>>>(x, wv, out_v, S_LEN, DKV, DMODEL);
    rope_kernel<ushort_t><<<(S_LEN * NHQ * 32 + 255) / 256, 256, 0, stream>>>(ws_q, cosT, sinT, NHQ);
    rope_kernel<float>   <<<(S_LEN * NKV * 32 + 255) / 256, 256, 0, stream>>>(out_k, cosT, sinT, NKV);
    kb_kernel<<<(S_LEN * DKV / 4) / 256, 256, 0, stream>>>(out_k, ws_kb);
    vt_kernel<<<dim3(S_LEN / 64, NKV), blk, 0, stream>>>(out_v, ws_vt);
    attn_mfma_old<<<NHQ * (S_LEN / 32), 64, 0, stream>>>(ws_q, ws_kb, ws_vt, ws_q);
    gemm_mfma_old<ushort_t, float><<<dim3(DMODEL / 128, S_LEN / 128), blk, 0, stream>>>(ws_q, wo, out, S_LEN, DMODEL, DMODEL);
  }
}